// Round 13
// baseline (180.656 us; speedup 1.0000x reference)
//
#include <hip/hip_runtime.h>
#include <hip/hip_bf16.h>

// Problem dims (fixed by reference): B=512, Q=64, S=36, D=1024, SIM=256
#define BB 512
#define QQ 64
#define SS 36
#define DD 1024
#define SIM 256

typedef unsigned short u16x8 __attribute__((ext_vector_type(8)));
typedef unsigned short u16x4 __attribute__((ext_vector_type(4)));
typedef __bf16 bf16x8 __attribute__((ext_vector_type(8)));
typedef float f32x4 __attribute__((ext_vector_type(4)));
typedef unsigned short us;

__device__ __forceinline__ us f2bf(float f) {
  unsigned u = __float_as_uint(f);
  u += 0x7FFFu + ((u >> 16) & 1u);   // round-to-nearest-even
  return (us)(u >> 16);
}
__device__ __forceinline__ float bf2f(us h) {
  return __uint_as_float(((unsigned)h) << 16);
}

// ---------------------------------------------------------------------------
// K0: one-shot W (256x1024 f32) -> bf16 row-major copy in ws. L2-resident.
// ---------------------------------------------------------------------------
__global__ __launch_bounds__(256) void k0_w16(const float* __restrict__ W,
                                              us* __restrict__ W16) {
  int i = blockIdx.x * 256 + threadIdx.x;  // 65536 float4s
  float4 v = ((const float4*)W)[i];
  ushort4 p;
  p.x = f2bf(v.x); p.y = f2bf(v.y); p.z = f2bf(v.z); p.w = f2bf(v.w);
  ((ushort4*)W16)[i] = p;
}

// ---------------------------------------------------------------------------
// K_FUSED v5: one batch per block, 512 thr (8 waves), 56.6KB STATIC LDS ->
// 2 blocks/CU (the R9-measured higher-duty-cycle regime), launch_bounds
// (512,4) caps VGPR at 128 (R11 measured 124 -> stash fits, no spill).
// vs v3 (142.4us best): ctx is chunk-tiled in LDS for phase A (13KB, not
// full-D 99KB); phase B re-stages ctx via R9's transposed-read loop
// (+75MB traffic traded for ~30% higher streaming rate). Query stash in
// registers (32 VGPR) kept -> phase B reads only ctx + W16.
//
// LDS map (static, byte offsets):
//   [0,19456)       ctxA us[48][136] (A, rows 36-47 zero) | ctxTs us[128][76] (B)
//   [19456,36864)   qmA us[64][136] (A) | sc f32[48][68] | A16s us[64][136] (B)
//   [36864,46080)   P16s us[64][72]
//   [46080,52992)   Gf16 us[48][72]
//   [52992,54016)   biasL f32[256]
//   [54016,54272)   rnL f32[64]
//   [54272,56576)   rsum f32[576]
// ---------------------------------------------------------------------------
template <bool USE_W16>
__global__ __launch_bounds__(512, 4) void k_fused(
    const float* __restrict__ query, const float* __restrict__ context,
    const float* __restrict__ matrix, const float* __restrict__ Wm,
    const float* __restrict__ bvec, const int* __restrict__ smoothp,
    const us* __restrict__ W16, float* __restrict__ out) {
  __shared__ __align__(16) char smem[56576];
  us* ctxA = (us*)smem;                    // [48][136] (phase A)
  us* ctxTs = (us*)smem;                   // [128][76] (phase B)
  us* qmA = (us*)(smem + 19456);           // [64][136] (phase A)
  float* sc = (float*)(smem + 19456);      // [48][68]  (bridge)
  us* A16s = (us*)(smem + 19456);          // [64][136] (phase B)
  us* P16s = (us*)(smem + 36864);          // [64][72]
  us* Gf16L = (us*)(smem + 46080);         // [48][72]
  float* biasL = (float*)(smem + 52992);   // [256]
  float* rnL = (float*)(smem + 54016);     // [64]
  float* rsum = (float*)(smem + 54272);    // [576]

  const int t = threadIdx.x, bb = blockIdx.x;
  const int lane = t & 63, w = t >> 6;
  const int ml = lane & 15, kg = lane >> 4;
  const float smf = (float)smoothp[0];

  // init: zero ctxA pad rows 36-47, P16/Gf16 pads; load bias
  for (int idx = t; idx < 816; idx += 512)
    ((unsigned*)(ctxA + 36 * 136))[idx] = 0;
  for (int idx = t; idx < 2304; idx += 512) ((unsigned*)P16s)[idx] = 0;
  for (int idx = t; idx < 1728; idx += 512) ((unsigned*)Gf16L)[idx] = 0;
  if (t < 256) biasL[t] = bvec[t];
  __syncthreads();  // pads visible before first MFMA phase

  // register stash of this thread's phase-B query slice:
  // element e=mt*4+ii of chunk ch is query[bb][mt*16+kg*4+ii][ch*128+w*16+ml]
  u16x8 qr0[8], qr1[8];
  const float* qcol = query + (size_t)bb * QQ * DD + w * 16 + ml;

  // ================= Phase A: scores + G (+query stash) =================
  f32x4 acc[3], gacc[3];
#pragma unroll
  for (int j = 0; j < 3; ++j) {
    acc[j] = (f32x4){0.f, 0.f, 0.f, 0.f};
    gacc[j] = (f32x4){0.f, 0.f, 0.f, 0.f};
  }

#pragma unroll
  for (int ch = 0; ch < 8; ++ch) {
    const int d0 = ch * 128;
    // stage qm = query*matrix bf16
#pragma unroll
    for (int i = 0; i < 2; ++i) {
      int idx = t + 512 * i;
      int row = idx >> 4, c8 = idx & 15;
      const float4* gq = (const float4*)&query[((size_t)bb * QQ + row) * DD + d0 + c8 * 8];
      const float4* gm = (const float4*)&matrix[((size_t)bb * QQ + row) * DD + d0 + c8 * 8];
      float4 a0 = gq[0], a1 = gq[1], m0 = gm[0], m1 = gm[1];
      u16x8 pk;
      pk[0] = f2bf(a0.x * m0.x); pk[1] = f2bf(a0.y * m0.y);
      pk[2] = f2bf(a0.z * m0.z); pk[3] = f2bf(a0.w * m0.w);
      pk[4] = f2bf(a1.x * m1.x); pk[5] = f2bf(a1.y * m1.y);
      pk[6] = f2bf(a1.z * m1.z); pk[7] = f2bf(a1.w * m1.w);
      *(u16x8*)&qmA[row * 136 + c8 * 8] = pk;
    }
    // stage ctx chunk (rows 0..31 by all, 32..35 by t<64)
    {
      int row = t >> 4, c8 = t & 15;
      const float4* gc = (const float4*)&context[((size_t)bb * SS + row) * DD + d0 + c8 * 8];
      float4 a0 = gc[0], a1 = gc[1];
      u16x8 pk;
      pk[0] = f2bf(a0.x); pk[1] = f2bf(a0.y); pk[2] = f2bf(a0.z); pk[3] = f2bf(a0.w);
      pk[4] = f2bf(a1.x); pk[5] = f2bf(a1.y); pk[6] = f2bf(a1.z); pk[7] = f2bf(a1.w);
      *(u16x8*)&ctxA[row * 136 + c8 * 8] = pk;
    }
    if (t < 64) {
      int row = 32 + (t >> 4), c8 = t & 15;
      const float4* gc = (const float4*)&context[((size_t)bb * SS + row) * DD + d0 + c8 * 8];
      float4 a0 = gc[0], a1 = gc[1];
      u16x8 pk;
      pk[0] = f2bf(a0.x); pk[1] = f2bf(a0.y); pk[2] = f2bf(a0.z); pk[3] = f2bf(a0.w);
      pk[4] = f2bf(a1.x); pk[5] = f2bf(a1.y); pk[6] = f2bf(a1.z); pk[7] = f2bf(a1.w);
      *(u16x8*)&ctxA[row * 136 + c8 * 8] = pk;
    }
    // issue query-stash loads (L2-hot: same chunk just staged above)
    float sv[16];
    {
#pragma unroll
      for (int j = 0; j < 16; ++j) {
        int q = (j >> 2) * 16 + kg * 4 + (j & 3);
        sv[j] = qcol[(size_t)q * DD + d0];
      }
    }
    __syncthreads();
#pragma unroll
    for (int ks = 0; ks < 4; ++ks) {
      const int ko = ks * 32 + kg * 8;
      if (w < 4) {  // scores: wave w -> q-cols w*16..+16
        bf16x8 bq = __builtin_bit_cast(bf16x8, *(const u16x8*)&qmA[(w * 16 + ml) * 136 + ko]);
#pragma unroll
        for (int mt = 0; mt < 3; ++mt) {
          bf16x8 af = __builtin_bit_cast(
              bf16x8, *(const u16x8*)&ctxA[(mt * 16 + ml) * 136 + ko]);
          acc[mt] = __builtin_amdgcn_mfma_f32_16x16x32_bf16(af, bq, acc[mt], 0, 0, 0);
        }
      } else if (w < 7) {  // G row-block w-4
        bf16x8 ai = __builtin_bit_cast(
            bf16x8, *(const u16x8*)&ctxA[((w - 4) * 16 + ml) * 136 + ko]);
#pragma unroll
        for (int j = 0; j < 3; ++j) {
          bf16x8 aj = __builtin_bit_cast(
              bf16x8, *(const u16x8*)&ctxA[(j * 16 + ml) * 136 + ko]);
          gacc[j] = __builtin_amdgcn_mfma_f32_16x16x32_bf16(ai, aj, gacc[j], 0, 0, 0);
        }
      }
    }
    // pack stash for this chunk (static indices -> stays in VGPRs)
    {
      u16x8 s0, s1;
#pragma unroll
      for (int j = 0; j < 8; ++j) {
        s0[j] = f2bf(sv[j]);
        s1[j] = f2bf(sv[8 + j]);
      }
      qr0[ch] = s0;
      qr1[ch] = s1;
    }
    __syncthreads();
  }

  // epilogue A: leaky -> sc (aliases qmA); G -> Gf16
  if (w < 4) {
#pragma unroll
    for (int mt = 0; mt < 3; ++mt)
#pragma unroll
      for (int ii = 0; ii < 4; ++ii) {
        float v = acc[mt][ii];
        v = v > 0.f ? v : 0.1f * v;
        sc[(mt * 16 + kg * 4 + ii) * 68 + w * 16 + ml] = v;
      }
  } else if (w < 7) {
#pragma unroll
    for (int j = 0; j < 3; ++j)
#pragma unroll
      for (int ii = 0; ii < 4; ++ii)
        Gf16L[((w - 4) * 16 + kg * 4 + ii) * 72 + j * 16 + ml] = f2bf(gacc[j][ii]);
  }
  __syncthreads();

  if (t < 36) {  // l2norm over q per row s
    float ssum = 0.f;
    for (int qi = 0; qi < 64; ++qi) { float v = sc[t * 68 + qi]; ssum = fmaf(v, v, ssum); }
    float rn = 1.f / (sqrtf(ssum) + 1e-8f);
    for (int qi = 0; qi < 64; ++qi) sc[t * 68 + qi] *= rn;
  }
  __syncthreads();

  if (t < 64) {  // softmax over s per column q -> P16
    float mx = -1e30f;
    for (int s2 = 0; s2 < 36; ++s2) mx = fmaxf(mx, sc[s2 * 68 + t]);
    float sum = 0.f;
    float ev[36];
    for (int s2 = 0; s2 < 36; ++s2) {
      float e = __expf((sc[s2 * 68 + t] - mx) * smf);
      ev[s2] = e;
      sum += e;
    }
    float rs = 1.f / sum;
#pragma unroll
    for (int s2 = 0; s2 < 36; ++s2) P16s[t * 72 + s2] = f2bf(ev[s2] * rs);
  }
  __syncthreads();

  // ================= Bridge: V = P.G^T -> rn_q; zero ctxT pads ===========
  if (w < 3) {
    f32x4 accv[4];
#pragma unroll
    for (int mt = 0; mt < 4; ++mt) accv[mt] = (f32x4){0.f, 0.f, 0.f, 0.f};
#pragma unroll
    for (int ks = 0; ks < 2; ++ks) {
      const int ko = ks * 32 + kg * 8;
      bf16x8 gfr = __builtin_bit_cast(bf16x8, *(const u16x8*)&Gf16L[(w * 16 + ml) * 72 + ko]);
#pragma unroll
      for (int mt = 0; mt < 4; ++mt) {
        bf16x8 pf = __builtin_bit_cast(bf16x8, *(const u16x8*)&P16s[(mt * 16 + ml) * 72 + ko]);
        accv[mt] = __builtin_amdgcn_mfma_f32_16x16x32_bf16(pf, gfr, accv[mt], 0, 0, 0);
      }
    }
#pragma unroll
    for (int mt = 0; mt < 4; ++mt)
#pragma unroll
      for (int ii = 0; ii < 4; ++ii) {
        int q = mt * 16 + kg * 4 + ii;
        float vv = accv[mt][ii] * bf2f(P16s[q * 72 + w * 16 + ml]);
        vv += __shfl_xor(vv, 1);
        vv += __shfl_xor(vv, 2);
        vv += __shfl_xor(vv, 4);
        vv += __shfl_xor(vv, 8);
        if (ml == 0) rsum[q * 4 + w] = vv;
      }
  }
  // zero ctxT pad cols [36,64) once (region1 is dead now; persists: phase B
  // staging writes only cols 0..35)
  for (int idx = t; idx < 1792; idx += 512) {
    int r = idx / 14, c = idx - r * 14;
    *(unsigned*)&ctxTs[r * 76 + 36 + c * 2] = 0;
  }
  __syncthreads();
  if (t < 64) {
    float s2 = rsum[t * 4] + rsum[t * 4 + 1] + rsum[t * 4 + 2];
    rnL[t] = 1.f / (sqrtf(s2) + 1e-8f);
  }
  __syncthreads();

  // ================= Phase B: ctxT -> wc -> A -> sim GEMM =================
  f32x4 accs[4][2];
#pragma unroll
  for (int mt = 0; mt < 4; ++mt)
#pragma unroll
    for (int ntl = 0; ntl < 2; ++ntl) accs[mt][ntl] = (f32x4){0.f, 0.f, 0.f, 0.f};

#pragma unroll
  for (int ch = 0; ch < 8; ++ch) {
    const int d0 = ch * 128;
    // (a) stage ctxT[d][s]: transposed global reads (ctx rows L2/L3-warm)
    for (int idx = t; idx < 1152; idx += 512) {
      int d = idx & 127, s0 = (idx >> 7) * 4;
      const float* cp = &context[((size_t)bb * SS + s0) * DD + d0 + d];
      u16x4 pk;
      pk[0] = f2bf(cp[0]);
      pk[1] = f2bf(cp[DD]);
      pk[2] = f2bf(cp[2 * DD]);
      pk[3] = f2bf(cp[3 * DD]);
      *(u16x4*)&ctxTs[d * 76 + s0] = pk;
    }
    __syncthreads();  // (b)
    // (c) wc = P.C : wave w owns d-cols [w*16, w*16+16)
    f32x4 aw[4];
#pragma unroll
    for (int mt = 0; mt < 4; ++mt) aw[mt] = (f32x4){0.f, 0.f, 0.f, 0.f};
#pragma unroll
    for (int ks = 0; ks < 2; ++ks) {
      const int ko = ks * 32 + kg * 8;
      u16x4 blo = *(const u16x4*)&ctxTs[(w * 16 + ml) * 76 + ko];
      u16x4 bhi = *(const u16x4*)&ctxTs[(w * 16 + ml) * 76 + ko + 4];
      bf16x8 bfr = __builtin_bit_cast(
          bf16x8, __builtin_shufflevector(blo, bhi, 0, 1, 2, 3, 4, 5, 6, 7));
#pragma unroll
      for (int mt = 0; mt < 4; ++mt) {
        bf16x8 af = __builtin_bit_cast(bf16x8, *(const u16x8*)&P16s[(mt * 16 + ml) * 72 + ko]);
        aw[mt] = __builtin_amdgcn_mfma_f32_16x16x32_bf16(af, bfr, aw[mt], 0, 0, 0);
      }
    }
    // (d) A = (q - wc*rn)^2 -> A16s bf16, query from register stash
#pragma unroll
    for (int mt = 0; mt < 4; ++mt)
#pragma unroll
      for (int ii = 0; ii < 4; ++ii) {
        int q = mt * 16 + kg * 4 + ii;
        const int e = mt * 4 + ii;
        float qv = bf2f(e < 8 ? qr0[ch][e] : qr1[ch][e - 8]);
        float av = qv - aw[mt][ii] * rnL[q];
        A16s[q * 136 + w * 16 + ml] = f2bf(av * av);
      }
    __syncthreads();  // (e)
    // (f) sim GEMM: wave w owns out cols [w*32, w*32+32)
#pragma unroll
    for (int ks = 0; ks < 4; ++ks) {
      const int ko = ks * 32 + kg * 8;
      bf16x8 bfr[2];
#pragma unroll
      for (int ntl = 0; ntl < 2; ++ntl) {
        const size_t wrow = (size_t)(w * 32 + ntl * 16 + ml);
        if constexpr (USE_W16) {
          bfr[ntl] = __builtin_bit_cast(bf16x8, *(const u16x8*)&W16[wrow * DD + d0 + ko]);
        } else {
          const float4* wp = (const float4*)&Wm[wrow * DD + d0 + ko];
          float4 x = wp[0], y = wp[1];
          u16x8 pk;
          pk[0] = f2bf(x.x); pk[1] = f2bf(x.y); pk[2] = f2bf(x.z); pk[3] = f2bf(x.w);
          pk[4] = f2bf(y.x); pk[5] = f2bf(y.y); pk[6] = f2bf(y.z); pk[7] = f2bf(y.w);
          bfr[ntl] = __builtin_bit_cast(bf16x8, pk);
        }
      }
#pragma unroll
      for (int mt = 0; mt < 4; ++mt) {
        bf16x8 af = __builtin_bit_cast(bf16x8, *(const u16x8*)&A16s[(mt * 16 + ml) * 136 + ko]);
#pragma unroll
        for (int ntl = 0; ntl < 2; ++ntl)
          accs[mt][ntl] =
              __builtin_amdgcn_mfma_f32_16x16x32_bf16(af, bfr[ntl], accs[mt][ntl], 0, 0, 0);
      }
    }
    __syncthreads();  // (g)
  }

  // ================= Epilogue B: +bias, l2norm(SIM), store =================
#pragma unroll
  for (int mt = 0; mt < 4; ++mt)
#pragma unroll
    for (int ii = 0; ii < 4; ++ii) {
      int q = mt * 16 + kg * 4 + ii;
      float partial = 0.f;
#pragma unroll
      for (int ntl = 0; ntl < 2; ++ntl) {
        int col = w * 32 + ntl * 16 + ml;
        float v = accs[mt][ntl][ii] + biasL[col];
        partial = fmaf(v, v, partial);
      }
      partial += __shfl_xor(partial, 1);
      partial += __shfl_xor(partial, 2);
      partial += __shfl_xor(partial, 4);
      partial += __shfl_xor(partial, 8);
      if (ml == 0) rsum[q * 9 + w] = partial;
    }
  __syncthreads();
  if (t < 64) {
    float ssum = 0.f;
#pragma unroll
    for (int w2 = 0; w2 < 8; ++w2) ssum += rsum[t * 9 + w2];
    rnL[t] = 1.f / (sqrtf(ssum) + 1e-8f);
  }
  __syncthreads();
#pragma unroll
  for (int mt = 0; mt < 4; ++mt)
#pragma unroll
    for (int ntl = 0; ntl < 2; ++ntl)
#pragma unroll
      for (int ii = 0; ii < 4; ++ii) {
        int q = mt * 16 + kg * 4 + ii;
        int col = w * 32 + ntl * 16 + ml;
        float v = accs[mt][ntl][ii] + biasL[col];
        out[((size_t)bb * QQ + q) * SIM + col] = v * rnL[q];
      }
}

extern "C" void kernel_launch(void* const* d_in, const int* in_sizes, int n_in,
                              void* d_out, int out_size, void* d_ws, size_t ws_size,
                              hipStream_t stream) {
  const float* query = (const float*)d_in[0];
  const float* context = (const float*)d_in[1];
  const float* matrix = (const float*)d_in[2];
  const float* Wm = (const float*)d_in[3];
  const float* bvec = (const float*)d_in[4];
  const int* smoothp = (const int*)d_in[5];
  float* out = (float*)d_out;

  us* W16 = (us*)d_ws;
  const bool useW16 = ws_size >= (size_t)SIM * DD * 2;

  if (useW16) {
    k0_w16<<<dim3(SIM * DD / 1024), dim3(256), 0, stream>>>(Wm, W16);
    k_fused<true><<<dim3(BB), dim3(512), 0, stream>>>(query, context, matrix, Wm,
                                                      bvec, smoothp, W16, out);
  } else {
    k_fused<false><<<dim3(BB), dim3(512), 0, stream>>>(query, context, matrix, Wm,
                                                       bvec, smoothp, W16, out);
  }
}

// Round 14
// 142.612 us; speedup vs baseline: 1.2668x; 1.2668x over previous
//
#include <hip/hip_runtime.h>
#include <hip/hip_bf16.h>

// Problem dims (fixed by reference): B=512, Q=64, S=36, D=1024, SIM=256
#define BB 512
#define QQ 64
#define SS 36
#define DD 1024
#define SIM 256

typedef unsigned short u16x8 __attribute__((ext_vector_type(8)));
typedef __bf16 bf16x8 __attribute__((ext_vector_type(8)));
typedef float f32x4 __attribute__((ext_vector_type(4)));
typedef unsigned short us;

__device__ __forceinline__ us f2bf(float f) {
  unsigned u = __float_as_uint(f);
  u += 0x7FFFu + ((u >> 16) & 1u);   // round-to-nearest-even
  return (us)(u >> 16);
}
__device__ __forceinline__ float bf2f(us h) {
  return __uint_as_float(((unsigned)h) << 16);
}

// ---------------------------------------------------------------------------
// K0: one-shot W (256x1024 f32) -> bf16 row-major copy in ws. L2-resident.
// ---------------------------------------------------------------------------
__global__ __launch_bounds__(256) void k0_w16(const float* __restrict__ W,
                                              us* __restrict__ W16) {
  int i = blockIdx.x * 256 + threadIdx.x;  // 65536 float4s
  float4 v = ((const float4*)W)[i];
  ushort4 p;
  p.x = f2bf(v.x); p.y = f2bf(v.y); p.z = f2bf(v.z); p.w = f2bf(v.w);
  ((ushort4*)W16)[i] = p;
}

// ---------------------------------------------------------------------------
// K_FUSED v3 (R11, measured best 142.4us): one batch per block, 512 thr
// (8 waves), 136.2KB dyn LDS, 1 block/CU. Each thread stashes its phase-B
// query fragment slice in registers during phase A (16 bf16 x 8 chunks =
// 64 VGPR), loaded L2-hot right after staging the same chunk. Phase B reads
// NO input globals (only W16, L2-resident 512KB). L2/L3-side bytes 377 MB
// (= input + output floor). Measured: VGPR 124, no spill.
//
// LDS map (byte offsets):
//   [0,99072)        ctxL us[48][1032]  full-D ctx bf16 (rows 36-47 zero)
//   [99072,116480)   X: qmL us[64][136] (A) | sc f32[48][68] | A16s (B)
//   [116480,125696)  P16s us[64][72]
//   [125696,132608)  Gf16 us[48][72]
//   [132608,133632)  biasL f32[256]
//   [133632,133888)  rnL f32[64]
//   [133888,136192)  rsum f32[576]
// ---------------------------------------------------------------------------
#define KF_LDS 136192

template <bool USE_W16>
__global__ __launch_bounds__(512, 2) void k_fused(
    const float* __restrict__ query, const float* __restrict__ context,
    const float* __restrict__ matrix, const float* __restrict__ Wm,
    const float* __restrict__ bvec, const int* __restrict__ smoothp,
    const us* __restrict__ W16, float* __restrict__ out) {
  extern __shared__ __align__(16) char smem[];
  us* ctxL = (us*)smem;                    // [48][1032]
  us* qmL = (us*)(smem + 99072);           // [64][136] (phase A)
  float* sc = (float*)(smem + 99072);      // [48][68]  (bridge)
  us* A16s = (us*)(smem + 99072);          // [64][136] (phase B)
  us* P16s = (us*)(smem + 116480);         // [64][72]
  us* Gf16L = (us*)(smem + 125696);        // [48][72]
  float* biasL = (float*)(smem + 132608);  // [256]
  float* rnL = (float*)(smem + 133632);    // [64]
  float* rsum = (float*)(smem + 133888);   // [576]

  const int t = threadIdx.x, bb = blockIdx.x;
  const int lane = t & 63, w = t >> 6;
  const int ml = lane & 15, kg = lane >> 4;
  const float smf = (float)smoothp[0];

  // init: zero ctxL rows 36-47, P16/Gf16 pads; load bias
  for (int idx = t; idx < 6192; idx += 512)
    ((unsigned*)(ctxL + 36 * 1032))[idx] = 0;
  for (int idx = t; idx < 2304; idx += 512) ((unsigned*)P16s)[idx] = 0;
  for (int idx = t; idx < 1728; idx += 512) ((unsigned*)Gf16L)[idx] = 0;
  if (t < 256) biasL[t] = bvec[t];

  // register stash of this thread's phase-B query slice:
  // element e=mt*4+ii of chunk ch is query[bb][mt*16+kg*4+ii][ch*128+w*16+ml]
  u16x8 qr0[8], qr1[8];  // e<8 (mt 0,1) | e>=8 (mt 2,3)

  // ================= Phase A: scores + G (+query stash) =================
  f32x4 acc[3], gacc[3];
#pragma unroll
  for (int j = 0; j < 3; ++j) {
    acc[j] = (f32x4){0.f, 0.f, 0.f, 0.f};
    gacc[j] = (f32x4){0.f, 0.f, 0.f, 0.f};
  }

#pragma unroll
  for (int ch = 0; ch < 8; ++ch) {
    const int d0 = ch * 128;
    // stage qm = query*matrix bf16
#pragma unroll
    for (int i = 0; i < 2; ++i) {
      int idx = t + 512 * i;
      int row = idx >> 4, c8 = idx & 15;
      const float4* gq = (const float4*)&query[((size_t)bb * QQ + row) * DD + d0 + c8 * 8];
      const float4* gm = (const float4*)&matrix[((size_t)bb * QQ + row) * DD + d0 + c8 * 8];
      float4 a0 = gq[0], a1 = gq[1], m0 = gm[0], m1 = gm[1];
      u16x8 pk;
      pk[0] = f2bf(a0.x * m0.x); pk[1] = f2bf(a0.y * m0.y);
      pk[2] = f2bf(a0.z * m0.z); pk[3] = f2bf(a0.w * m0.w);
      pk[4] = f2bf(a1.x * m1.x); pk[5] = f2bf(a1.y * m1.y);
      pk[6] = f2bf(a1.z * m1.z); pk[7] = f2bf(a1.w * m1.w);
      *(u16x8*)&qmL[row * 136 + c8 * 8] = pk;
    }
    // stage ctx into FULL-D ctxL (rows 0..31 by all, 32..35 by t<64)
    {
      int row = t >> 4, c8 = t & 15;
      const float4* gc = (const float4*)&context[((size_t)bb * SS + row) * DD + d0 + c8 * 8];
      float4 a0 = gc[0], a1 = gc[1];
      u16x8 pk;
      pk[0] = f2bf(a0.x); pk[1] = f2bf(a0.y); pk[2] = f2bf(a0.z); pk[3] = f2bf(a0.w);
      pk[4] = f2bf(a1.x); pk[5] = f2bf(a1.y); pk[6] = f2bf(a1.z); pk[7] = f2bf(a1.w);
      *(u16x8*)&ctxL[row * 1032 + d0 + c8 * 8] = pk;
    }
    if (t < 64) {
      int row = 32 + (t >> 4), c8 = t & 15;
      const float4* gc = (const float4*)&context[((size_t)bb * SS + row) * DD + d0 + c8 * 8];
      float4 a0 = gc[0], a1 = gc[1];
      u16x8 pk;
      pk[0] = f2bf(a0.x); pk[1] = f2bf(a0.y); pk[2] = f2bf(a0.z); pk[3] = f2bf(a0.w);
      pk[4] = f2bf(a1.x); pk[5] = f2bf(a1.y); pk[6] = f2bf(a1.z); pk[7] = f2bf(a1.w);
      *(u16x8*)&ctxL[row * 1032 + d0 + c8 * 8] = pk;
    }
    // issue query-stash loads (L2-hot: same chunk just staged above);
    // latency hides under the barrier + MFMA phase.
    float sv[16];
    {
      const float* qcol = query + (size_t)bb * QQ * DD + d0 + w * 16 + ml;
#pragma unroll
      for (int j = 0; j < 16; ++j) {
        int q = (j >> 2) * 16 + kg * 4 + (j & 3);
        sv[j] = qcol[(size_t)q * DD];
      }
    }
    __syncthreads();
#pragma unroll
    for (int ks = 0; ks < 4; ++ks) {
      const int ko = ks * 32 + kg * 8;
      if (w < 4) {  // scores: wave w -> q-cols w*16..+16
        bf16x8 bq = __builtin_bit_cast(bf16x8, *(const u16x8*)&qmL[(w * 16 + ml) * 136 + ko]);
#pragma unroll
        for (int mt = 0; mt < 3; ++mt) {
          bf16x8 af = __builtin_bit_cast(
              bf16x8, *(const u16x8*)&ctxL[(mt * 16 + ml) * 1032 + d0 + ko]);
          acc[mt] = __builtin_amdgcn_mfma_f32_16x16x32_bf16(af, bq, acc[mt], 0, 0, 0);
        }
      } else if (w < 7) {  // G row-block w-4
        bf16x8 ai = __builtin_bit_cast(
            bf16x8, *(const u16x8*)&ctxL[((w - 4) * 16 + ml) * 1032 + d0 + ko]);
#pragma unroll
        for (int j = 0; j < 3; ++j) {
          bf16x8 aj = __builtin_bit_cast(
              bf16x8, *(const u16x8*)&ctxL[(j * 16 + ml) * 1032 + d0 + ko]);
          gacc[j] = __builtin_amdgcn_mfma_f32_16x16x32_bf16(ai, aj, gacc[j], 0, 0, 0);
        }
      }
    }
    // pack stash for this chunk (static indices -> stays in VGPRs)
    {
      u16x8 s0, s1;
#pragma unroll
      for (int j = 0; j < 8; ++j) {
        s0[j] = f2bf(sv[j]);
        s1[j] = f2bf(sv[8 + j]);
      }
      qr0[ch] = s0;
      qr1[ch] = s1;
    }
    __syncthreads();
  }

  // epilogue A: leaky -> sc (aliases qmL); G -> Gf16
  if (w < 4) {
#pragma unroll
    for (int mt = 0; mt < 3; ++mt)
#pragma unroll
      for (int ii = 0; ii < 4; ++ii) {
        float v = acc[mt][ii];
        v = v > 0.f ? v : 0.1f * v;
        sc[(mt * 16 + kg * 4 + ii) * 68 + w * 16 + ml] = v;
      }
  } else if (w < 7) {
#pragma unroll
    for (int j = 0; j < 3; ++j)
#pragma unroll
      for (int ii = 0; ii < 4; ++ii)
        Gf16L[((w - 4) * 16 + kg * 4 + ii) * 72 + j * 16 + ml] = f2bf(gacc[j][ii]);
  }
  __syncthreads();

  if (t < 36) {  // l2norm over q per row s
    float ssum = 0.f;
    for (int qi = 0; qi < 64; ++qi) { float v = sc[t * 68 + qi]; ssum = fmaf(v, v, ssum); }
    float rn = 1.f / (sqrtf(ssum) + 1e-8f);
    for (int qi = 0; qi < 64; ++qi) sc[t * 68 + qi] *= rn;
  }
  __syncthreads();

  if (t < 64) {  // softmax over s per column q -> P16
    float mx = -1e30f;
    for (int s2 = 0; s2 < 36; ++s2) mx = fmaxf(mx, sc[s2 * 68 + t]);
    float sum = 0.f;
    float ev[36];
    for (int s2 = 0; s2 < 36; ++s2) {
      float e = __expf((sc[s2 * 68 + t] - mx) * smf);
      ev[s2] = e;
      sum += e;
    }
    float rs = 1.f / sum;
#pragma unroll
    for (int s2 = 0; s2 < 36; ++s2) P16s[t * 72 + s2] = f2bf(ev[s2] * rs);
  }
  __syncthreads();

  // ================= Bridge: V = P.G^T -> rn_q =================
  if (w < 3) {
    f32x4 accv[4];
#pragma unroll
    for (int mt = 0; mt < 4; ++mt) accv[mt] = (f32x4){0.f, 0.f, 0.f, 0.f};
#pragma unroll
    for (int ks = 0; ks < 2; ++ks) {
      const int ko = ks * 32 + kg * 8;
      bf16x8 gfr = __builtin_bit_cast(bf16x8, *(const u16x8*)&Gf16L[(w * 16 + ml) * 72 + ko]);
#pragma unroll
      for (int mt = 0; mt < 4; ++mt) {
        bf16x8 pf = __builtin_bit_cast(bf16x8, *(const u16x8*)&P16s[(mt * 16 + ml) * 72 + ko]);
        accv[mt] = __builtin_amdgcn_mfma_f32_16x16x32_bf16(pf, gfr, accv[mt], 0, 0, 0);
      }
    }
#pragma unroll
    for (int mt = 0; mt < 4; ++mt)
#pragma unroll
      for (int ii = 0; ii < 4; ++ii) {
        int q = mt * 16 + kg * 4 + ii;
        float vv = accv[mt][ii] * bf2f(P16s[q * 72 + w * 16 + ml]);
        vv += __shfl_xor(vv, 1);
        vv += __shfl_xor(vv, 2);
        vv += __shfl_xor(vv, 4);
        vv += __shfl_xor(vv, 8);
        if (ml == 0) rsum[q * 4 + w] = vv;
      }
  }
  __syncthreads();
  if (t < 64) {
    float s2 = rsum[t * 4] + rsum[t * 4 + 1] + rsum[t * 4 + 2];
    rnL[t] = 1.f / (sqrtf(s2) + 1e-8f);
  }
  __syncthreads();

  // ================= Phase B: wc -> A -> sim GEMM (no input globals) ======
  f32x4 accs[4][2];
#pragma unroll
  for (int mt = 0; mt < 4; ++mt)
#pragma unroll
    for (int ntl = 0; ntl < 2; ++ntl) accs[mt][ntl] = (f32x4){0.f, 0.f, 0.f, 0.f};

#pragma unroll
  for (int ch = 0; ch < 8; ++ch) {
    const int d0 = ch * 128;
    // (c) wc = P.C : B-frags gathered from full-D ctxL (K = s, padded 64)
    f32x4 aw[4];
#pragma unroll
    for (int mt = 0; mt < 4; ++mt) aw[mt] = (f32x4){0.f, 0.f, 0.f, 0.f};
    {
      const int ncol = d0 + w * 16 + ml;
      u16x8 g0;
#pragma unroll
      for (int j = 0; j < 8; ++j) g0[j] = ctxL[(kg * 8 + j) * 1032 + ncol];
      bf16x8 bfr0 = __builtin_bit_cast(bf16x8, g0);
#pragma unroll
      for (int mt = 0; mt < 4; ++mt) {
        bf16x8 af = __builtin_bit_cast(bf16x8, *(const u16x8*)&P16s[(mt * 16 + ml) * 72 + kg * 8]);
        aw[mt] = __builtin_amdgcn_mfma_f32_16x16x32_bf16(af, bfr0, aw[mt], 0, 0, 0);
      }
      u16x8 g1;
#pragma unroll
      for (int j = 0; j < 8; ++j)
        g1[j] = (kg < 2) ? ctxL[(32 + kg * 8 + j) * 1032 + ncol] : (us)0;
      bf16x8 bfr1 = __builtin_bit_cast(bf16x8, g1);
#pragma unroll
      for (int mt = 0; mt < 4; ++mt) {
        bf16x8 af =
            __builtin_bit_cast(bf16x8, *(const u16x8*)&P16s[(mt * 16 + ml) * 72 + 32 + kg * 8]);
        aw[mt] = __builtin_amdgcn_mfma_f32_16x16x32_bf16(af, bfr1, aw[mt], 0, 0, 0);
      }
    }
    __syncthreads();  // prev chunk's (f) reads of A16s done
    // (d) A = (q - wc*rn)^2 -> A16s bf16, query from register stash
#pragma unroll
    for (int mt = 0; mt < 4; ++mt)
#pragma unroll
      for (int ii = 0; ii < 4; ++ii) {
        int q = mt * 16 + kg * 4 + ii;
        const int e = mt * 4 + ii;
        float qv = bf2f(e < 8 ? qr0[ch][e] : qr1[ch][e - 8]);
        float av = qv - aw[mt][ii] * rnL[q];
        A16s[q * 136 + w * 16 + ml] = f2bf(av * av);
      }
    __syncthreads();
    // (f) sim GEMM: wave w owns out cols [w*32, w*32+32)
#pragma unroll
    for (int ks = 0; ks < 4; ++ks) {
      const int ko = ks * 32 + kg * 8;
      bf16x8 bfr[2];
#pragma unroll
      for (int ntl = 0; ntl < 2; ++ntl) {
        const size_t wrow = (size_t)(w * 32 + ntl * 16 + ml);
        if constexpr (USE_W16) {
          bfr[ntl] = __builtin_bit_cast(bf16x8, *(const u16x8*)&W16[wrow * DD + d0 + ko]);
        } else {
          const float4* wp = (const float4*)&Wm[wrow * DD + d0 + ko];
          float4 x = wp[0], y = wp[1];
          u16x8 pk;
          pk[0] = f2bf(x.x); pk[1] = f2bf(x.y); pk[2] = f2bf(x.z); pk[3] = f2bf(x.w);
          pk[4] = f2bf(y.x); pk[5] = f2bf(y.y); pk[6] = f2bf(y.z); pk[7] = f2bf(y.w);
          bfr[ntl] = __builtin_bit_cast(bf16x8, pk);
        }
      }
#pragma unroll
      for (int mt = 0; mt < 4; ++mt) {
        bf16x8 af = __builtin_bit_cast(bf16x8, *(const u16x8*)&A16s[(mt * 16 + ml) * 136 + ko]);
#pragma unroll
        for (int ntl = 0; ntl < 2; ++ntl)
          accs[mt][ntl] =
              __builtin_amdgcn_mfma_f32_16x16x32_bf16(af, bfr[ntl], accs[mt][ntl], 0, 0, 0);
      }
    }
  }
  __syncthreads();

  // ================= Epilogue B: +bias, l2norm(SIM), store =================
#pragma unroll
  for (int mt = 0; mt < 4; ++mt)
#pragma unroll
    for (int ii = 0; ii < 4; ++ii) {
      int q = mt * 16 + kg * 4 + ii;
      float partial = 0.f;
#pragma unroll
      for (int ntl = 0; ntl < 2; ++ntl) {
        int col = w * 32 + ntl * 16 + ml;
        float v = accs[mt][ntl][ii] + biasL[col];
        partial = fmaf(v, v, partial);
      }
      partial += __shfl_xor(partial, 1);
      partial += __shfl_xor(partial, 2);
      partial += __shfl_xor(partial, 4);
      partial += __shfl_xor(partial, 8);
      if (ml == 0) rsum[q * 9 + w] = partial;
    }
  __syncthreads();
  if (t < 64) {
    float ssum = 0.f;
#pragma unroll
    for (int w2 = 0; w2 < 8; ++w2) ssum += rsum[t * 9 + w2];
    rnL[t] = 1.f / (sqrtf(ssum) + 1e-8f);
  }
  __syncthreads();
#pragma unroll
  for (int mt = 0; mt < 4; ++mt)
#pragma unroll
    for (int ntl = 0; ntl < 2; ++ntl)
#pragma unroll
      for (int ii = 0; ii < 4; ++ii) {
        int q = mt * 16 + kg * 4 + ii;
        int col = w * 32 + ntl * 16 + ml;
        float v = accs[mt][ntl][ii] + biasL[col];
        out[((size_t)bb * QQ + q) * SIM + col] = v * rnL[q];
      }
}

extern "C" void kernel_launch(void* const* d_in, const int* in_sizes, int n_in,
                              void* d_out, int out_size, void* d_ws, size_t ws_size,
                              hipStream_t stream) {
  const float* query = (const float*)d_in[0];
  const float* context = (const float*)d_in[1];
  const float* matrix = (const float*)d_in[2];
  const float* Wm = (const float*)d_in[3];
  const float* bvec = (const float*)d_in[4];
  const int* smoothp = (const int*)d_in[5];
  float* out = (float*)d_out;

  us* W16 = (us*)d_ws;
  const bool useW16 = ws_size >= (size_t)SIM * DD * 2;

  hipFuncSetAttribute((const void*)k_fused<true>,
                      hipFuncAttributeMaxDynamicSharedMemorySize, KF_LDS);
  hipFuncSetAttribute((const void*)k_fused<false>,
                      hipFuncAttributeMaxDynamicSharedMemorySize, KF_LDS);

  if (useW16) {
    k0_w16<<<dim3(SIM * DD / 1024), dim3(256), 0, stream>>>(Wm, W16);
    k_fused<true><<<dim3(BB), dim3(512), KF_LDS, stream>>>(query, context, matrix, Wm,
                                                           bvec, smoothp, W16, out);
  } else {
    k_fused<false><<<dim3(BB), dim3(512), KF_LDS, stream>>>(query, context, matrix, Wm,
                                                            bvec, smoothp, W16, out);
  }
}